// Round 3
// baseline (51.534 us; speedup 1.0000x reference)
//
#include <hip/hip_runtime.h>

#define S 1024
#define B 32
#define D 1024
#define NCH 32          // s-chunks in fused kernel
#define CH (S / NCH)    // 32 rows per block
#define RPW (CH / 4)    // 8 rows per wave
#define ECH 16          // e-chunks in k1
#define EC (D / ECH)    // 64 e per chunk

// k1: g[b,d] = sum_e h[b,e] * W[e,d].  W read exactly once (4 MB).
__global__ __launch_bounds__(256) void k1_gW(const float* __restrict__ hid,
                                             const float* __restrict__ W,
                                             float* __restrict__ g) {
    const int tid = threadIdx.x;
    const int d   = blockIdx.x * 256 + tid;
    const int e0  = blockIdx.y * EC;
    __shared__ float4 sh[EC * 8];          // [e][j], j-th float4 = batches 4j..4j+3
    for (int k = 0; k < (EC * 32) / 256; ++k) {
        int lin = tid + k * 256;
        int b = lin >> 6;
        int e = lin & (EC - 1);
        ((float*)sh)[e * 32 + b] = hid[b * D + e0 + e];
    }
    __syncthreads();
    float acc[32];
    #pragma unroll
    for (int b = 0; b < 32; ++b) acc[b] = 0.f;
    for (int e = 0; e < EC; ++e) {
        float w = W[(size_t)(e0 + e) * D + d];
        #pragma unroll
        for (int j = 0; j < 8; ++j) {
            float4 hv = sh[e * 8 + j];
            acc[4 * j + 0] += hv.x * w;
            acc[4 * j + 1] += hv.y * w;
            acc[4 * j + 2] += hv.z * w;
            acc[4 * j + 3] += hv.w * w;
        }
    }
    #pragma unroll
    for (int b = 0; b < 32; ++b) atomicAdd(&g[b * D + d], acc[b]);
}

// k2: fused logits + online-softmax + partial weighted sum. enc read ONCE.
// Grid (NCH, B). Each 64-lane WAVE owns RPW whole rows (16 floats/lane over D);
// dot via shfl_xor butterfly (no LDS, no barriers in loop). One end-of-block
// merge of the 4 waves' (m,l,acc) partials through LDS.
__global__ __launch_bounds__(256) void k2_fused(const float* __restrict__ enc,
                                                const float* __restrict__ g,
                                                float* __restrict__ logits,
                                                float* __restrict__ marr,
                                                float* __restrict__ larr,
                                                float* __restrict__ pacc) {
    const int tid  = threadIdx.x;
    const int lane = tid & 63;
    const int wid  = tid >> 6;
    const int c    = blockIdx.x;
    const int b    = blockIdx.y;

    // g fragment: lane holds d = j*256 + 4*lane .. +3
    const float4* gp = (const float4*)(g + b * D);
    float4 gv[4];
    #pragma unroll
    for (int j = 0; j < 4; ++j) gv[j] = gp[j * 64 + lane];

    const float4* encb = (const float4*)enc;
    const int row0 = c * CH + wid * RPW;
    const size_t rstride = (size_t)B * (D / 4);              // float4 per s-row
    size_t base = ((size_t)row0 * B + b) * (D / 4) + lane;

    float4 cur[4], nxt[4];
    #pragma unroll
    for (int j = 0; j < 4; ++j) cur[j] = encb[base + j * 64];

    float m = -3.0e38f, l = 0.f;
    float4 acc[4] = {{0,0,0,0},{0,0,0,0},{0,0,0,0},{0,0,0,0}};

    for (int i = 0; i < RPW; ++i) {
        if (i + 1 < RPW) {
            size_t nb = base + (size_t)(i + 1) * rstride;
            #pragma unroll
            for (int j = 0; j < 4; ++j) nxt[j] = encb[nb + j * 64];
        }
        float pd = 0.f;
        #pragma unroll
        for (int j = 0; j < 4; ++j)
            pd += cur[j].x * gv[j].x + cur[j].y * gv[j].y +
                  cur[j].z * gv[j].z + cur[j].w * gv[j].w;
        #pragma unroll
        for (int off = 1; off < 64; off <<= 1)
            pd += __shfl_xor(pd, off, 64);                    // sum in ALL lanes
        if (lane == 0) logits[b * S + row0 + i] = pd;
        float mn = fmaxf(m, pd);
        float sc = __expf(m - mn);
        float p  = __expf(pd - mn);
        l = l * sc + p;
        #pragma unroll
        for (int j = 0; j < 4; ++j) {
            acc[j].x = acc[j].x * sc + p * cur[j].x;
            acc[j].y = acc[j].y * sc + p * cur[j].y;
            acc[j].z = acc[j].z * sc + p * cur[j].z;
            acc[j].w = acc[j].w * sc + p * cur[j].w;
        }
        m = mn;
        #pragma unroll
        for (int j = 0; j < 4; ++j) cur[j] = nxt[j];
    }

    // Block merge: 4 waves -> one (m,l,acc) per (c,b).
    __shared__ float4 sacc[4][256];   // 16 KB
    __shared__ float  sm[4], sl[4];
    #pragma unroll
    for (int j = 0; j < 4; ++j) sacc[wid][j * 64 + lane] = acc[j];
    if (lane == 0) { sm[wid] = m; sl[wid] = l; }
    __syncthreads();
    float mg = fmaxf(fmaxf(sm[0], sm[1]), fmaxf(sm[2], sm[3]));
    float4 r = {0, 0, 0, 0};
    float lsum = 0.f;
    #pragma unroll
    for (int w = 0; w < 4; ++w) {
        float fw = __expf(sm[w] - mg);
        float4 a = sacc[w][wid * 64 + lane];
        r.x += a.x * fw; r.y += a.y * fw; r.z += a.z * fw; r.w += a.w * fw;
        lsum += sl[w] * fw;
    }
    ((float4*)pacc)[(size_t)(c * B + b) * (D / 4) + wid * 64 + lane] = r;
    if (tid == 0) { marr[c * B + b] = mg; larr[c * B + b] = lsum; }
}

// k3: merge per-chunk partials -> reps; normalize logits -> alpha.
__global__ __launch_bounds__(256) void k3_combine(const float* __restrict__ logits,
                                                  const float* __restrict__ marr,
                                                  const float* __restrict__ larr,
                                                  const float* __restrict__ pacc,
                                                  float* __restrict__ out) {
    const int tid = threadIdx.x;
    const int q   = blockIdx.x;
    const int b   = blockIdx.y;
    __shared__ float shm[NCH], shl[NCH];
    if (tid < NCH) { shm[tid] = marr[tid * B + b]; shl[tid] = larr[tid * B + b]; }
    __syncthreads();
    float mg = -3.0e38f;
    #pragma unroll
    for (int c = 0; c < NCH; ++c) mg = fmaxf(mg, shm[c]);
    const int d = q * 256 + tid;
    float lg = 0.f, racc = 0.f;
    #pragma unroll 4
    for (int c = 0; c < NCH; ++c) {
        float fc = __expf(shm[c] - mg);
        lg   += shl[c] * fc;
        racc += pacc[(size_t)(c * B + b) * D + d] * fc;
    }
    float inv = 1.f / lg;
    out[b * D + d] = racc * inv;                                   // reps [B,1,D]
    int s = q * 256 + tid;
    out[B * D + b * S + s] = __expf(logits[b * S + s] - mg) * inv; // alpha [B,1,S]
}

extern "C" void kernel_launch(void* const* d_in, const int* in_sizes, int n_in,
                              void* d_out, int out_size, void* d_ws, size_t ws_size,
                              hipStream_t stream) {
    const float* hid = (const float*)d_in[0];  // (2,B,H) flat == h[B, D]
    const float* enc = (const float*)d_in[1];  // (S,B,D)
    const float* W   = (const float*)d_in[2];  // (D,D)
    // d_in[3] = bias: per-b constant in logits -> cancels in softmax.

    float* out = (float*)d_out;

    float* g      = (float*)d_ws;          // B*D
    float* logits = g + B * D;             // B*S
    float* marr   = logits + B * S;        // NCH*B
    float* larr   = marr + NCH * B;        // NCH*B
    float* pacc   = larr + NCH * B;        // NCH*B*D (4 MB)

    hipMemsetAsync(g, 0, B * D * sizeof(float), stream);
    k1_gW<<<dim3(D / 256, ECH), 256, 0, stream>>>(hid, W, g);
    k2_fused<<<dim3(NCH, B), 256, 0, stream>>>(enc, g, logits, marr, larr, pacc);
    k3_combine<<<dim3(4, B), 256, 0, stream>>>(logits, marr, larr, pacc, out);
}